// Round 1
// baseline (1220.051 us; speedup 1.0000x reference)
//
#include <hip/hip_runtime.h>

#define NN 50000
#define NE 800000
#define HD 64

__device__ __forceinline__ float wave_sum(float v) {
#pragma unroll
  for (int off = 32; off > 0; off >>= 1) v += __shfl_xor(v, off, 64);
  return v;
}

// ---------------- CSR build ----------------
__global__ void zero_int_kernel(int* __restrict__ p, int n) {
  int i = blockIdx.x * blockDim.x + threadIdx.x;
  if (i < n) p[i] = 0;
}

__global__ void count_kernel(const int* __restrict__ dst, int* __restrict__ deg) {
  int e = blockIdx.x * blockDim.x + threadIdx.x;
  if (e < NE) atomicAdd(&deg[dst[e]], 1);
}

__global__ __launch_bounds__(1024) void scan_kernel(const int* __restrict__ deg,
                                                    int* __restrict__ rowptr,
                                                    int* __restrict__ cursor) {
  __shared__ int part[1024];
  const int t = threadIdx.x;
  const int chunk = (NN + 1023) / 1024;
  const int lo = min(t * chunk, NN);
  const int hi = min(lo + chunk, NN);
  int sum = 0;
  for (int i = lo; i < hi; ++i) sum += deg[i];
  part[t] = sum;
  __syncthreads();
  for (int off = 1; off < 1024; off <<= 1) {
    int mine = part[t];
    int add = (t >= off) ? part[t - off] : 0;
    __syncthreads();
    part[t] = mine + add;
    __syncthreads();
  }
  int base = (t > 0) ? part[t - 1] : 0;
  for (int i = lo; i < hi; ++i) {
    rowptr[i] = base;
    cursor[i] = base;
    base += deg[i];
  }
  if (t == 0) rowptr[NN] = part[1023];
}

__global__ void scatter_kernel(const int* __restrict__ src, const int* __restrict__ dst,
                               int* __restrict__ cursor, int2* __restrict__ csr_se) {
  int e = blockIdx.x * blockDim.x + threadIdx.x;
  if (e < NE) {
    int d = dst[e];
    int pos = atomicAdd(&cursor[d], 1);
    csr_se[pos] = make_int2(src[e], e);
  }
}

// ---------------- node encoder: x[N,128] @ Wn[128,64] + bn ----------------
__global__ __launch_bounds__(256) void encoder_kernel(const float* __restrict__ x,
                                                      const float* __restrict__ Wn,
                                                      const float* __restrict__ bn,
                                                      float* __restrict__ out) {
  const int w = threadIdx.x >> 6, h = threadIdx.x & 63;
  const int v = blockIdx.x * 4 + w;
  __shared__ float sx[4][128];
  sx[w][h] = x[(size_t)v * 128 + h];
  sx[w][64 + h] = x[(size_t)v * 128 + 64 + h];
  __syncthreads();
  float acc = bn[h];
#pragma unroll 8
  for (int k = 0; k < 128; ++k) acc += sx[w][k] * Wn[k * 64 + h];
  out[(size_t)v * 64 + h] = acc;
}

// ---------------- relu(layernorm(x)) for DeepGCN res+ blocks ----------------
__global__ __launch_bounds__(256) void lnrelu_kernel(const float* __restrict__ x,
                                                     const float* __restrict__ g,
                                                     const float* __restrict__ b,
                                                     int layer, float* __restrict__ out) {
  const int w = threadIdx.x >> 6, h = threadIdx.x & 63;
  const int v = blockIdx.x * 4 + w;
  float val = x[(size_t)v * 64 + h];
  float mu = wave_sum(val) * (1.f / 64.f);
  float d = val - mu;
  float var = wave_sum(d * d) * (1.f / 64.f);
  float r = rsqrtf(var + 1e-5f);
  out[(size_t)v * 64 + h] = fmaxf(d * r * g[layer * 64 + h] + b[layer * 64 + h], 0.f);
}

// ---------------- GENConv: online per-channel segment softmax + fused MLP ----------------
__global__ __launch_bounds__(256) void conv_kernel(
    const float* __restrict__ in,      // conv input [N,64] (gather table + root residual)
    const float* __restrict__ resid,   // outer residual x (null for layer 0)
    float* __restrict__ out,           // [N,64]
    const int* __restrict__ rowptr, const int2* __restrict__ csr_se,
    const float* __restrict__ eattr,   // [E,8]
    const float* __restrict__ We,      // [8,64]
    const float* __restrict__ be,      // [64]
    const float* __restrict__ tptr, int layer,
    const float* __restrict__ W1b, const float* __restrict__ b1b,
    const float* __restrict__ g1b, const float* __restrict__ c1b,
    const float* __restrict__ W2b, const float* __restrict__ b2b) {
  const int w = threadIdx.x >> 6, h = threadIdx.x & 63;
  const int v = blockIdx.x * 4 + w;
  const float* W1 = W1b + layer * 64 * 128;
  const float* b1 = b1b + layer * 128;
  const float* g1 = g1b + layer * 128;
  const float* c1 = c1b + layer * 128;
  const float* W2 = W2b + layer * 128 * 64;
  const float* b2 = b2b + layer * 64;
  const float t = tptr[layer];

  float we[8];
#pragma unroll
  for (int k = 0; k < 8; ++k) we[k] = We[k * 64 + h];
  const float beh = be[h];

  // online softmax aggregation over in-edges (per-lane == per-channel)
  float m = -1e30f, s = 0.f, o = 0.f;
  const int i0 = rowptr[v], i1 = rowptr[v + 1];
  for (int i = i0; i < i1; ++i) {
    const int2 se = csr_se[i];
    const float4 ea0 = *(const float4*)(eattr + (size_t)se.y * 8);
    const float4 ea1 = *(const float4*)(eattr + (size_t)se.y * 8 + 4);
    float eh = beh + ea0.x * we[0] + ea0.y * we[1] + ea0.z * we[2] + ea0.w * we[3]
                   + ea1.x * we[4] + ea1.y * we[5] + ea1.z * we[6] + ea1.w * we[7];
    const float xv = in[(size_t)se.x * 64 + h];
    float msg = fmaxf(xv + eh, 0.f) + 1e-7f;
    float l = msg * t;
    float mn = fmaxf(m, l);
    float c = __expf(m - mn);
    float p = __expf(l - mn);
    s = s * c + p;
    o = o * c + msg * p;
    m = mn;
  }
  float agg = o / (s + 1e-16f) + in[(size_t)v * 64 + h];  // root residual

  // MLP: Linear(64,128) -> LN -> ReLU -> Linear(128,64)
  __shared__ float sh[4][64];
  __shared__ float sh2[4][128];
  sh[w][h] = agg;
  __syncthreads();
  float u0 = b1[h], u1 = b1[64 + h];
#pragma unroll 8
  for (int k = 0; k < 64; ++k) {
    float a = sh[w][k];
    u0 += a * W1[k * 128 + h];
    u1 += a * W1[k * 128 + 64 + h];
  }
  float mu = wave_sum(u0 + u1) * (1.f / 128.f);
  float d0 = u0 - mu, d1 = u1 - mu;
  float var = wave_sum(d0 * d0 + d1 * d1) * (1.f / 128.f);
  float r = rsqrtf(var + 1e-5f);
  float h0 = fmaxf(d0 * r * g1[h] + c1[h], 0.f);
  float h1 = fmaxf(d1 * r * g1[64 + h] + c1[64 + h], 0.f);
  sh2[w][h] = h0;
  sh2[w][64 + h] = h1;
  __syncthreads();
  float acc = b2[h];
#pragma unroll 8
  for (int k = 0; k < 128; ++k) acc += sh2[w][k] * W2[k * 64 + h];
  if (resid) acc += resid[(size_t)v * 64 + h];
  out[(size_t)v * 64 + h] = acc;
}

// ---------------- head: relu(LN(x, gL[0], bL[0])) @ Wo[64,112] + bo ----------------
__global__ __launch_bounds__(256) void head_kernel(const float* __restrict__ x,
                                                   const float* __restrict__ gL,
                                                   const float* __restrict__ bL,
                                                   const float* __restrict__ Wo,
                                                   const float* __restrict__ bo,
                                                   float* __restrict__ out) {
  const int w = threadIdx.x >> 6, h = threadIdx.x & 63;
  const int v = blockIdx.x * 4 + w;
  float val = x[(size_t)v * 64 + h];
  float mu = wave_sum(val) * (1.f / 64.f);
  float d = val - mu;
  float var = wave_sum(d * d) * (1.f / 64.f);
  float r = rsqrtf(var + 1e-5f);
  float hv = fmaxf(d * r * gL[h] + bL[h], 0.f);
  __shared__ float sh[4][64];
  sh[w][h] = hv;
  __syncthreads();
  float o0 = bo[h];
  float o1 = (h < 48) ? bo[64 + h] : 0.f;
  for (int k = 0; k < 64; ++k) {
    float a = sh[w][k];
    o0 += a * Wo[k * 112 + h];
    if (h < 48) o1 += a * Wo[k * 112 + 64 + h];
  }
  out[(size_t)v * 112 + h] = o0;
  if (h < 48) out[(size_t)v * 112 + 64 + h] = o1;
}

extern "C" void kernel_launch(void* const* d_in, const int* in_sizes, int n_in,
                              void* d_out, int out_size, void* d_ws, size_t ws_size,
                              hipStream_t stream) {
  const float* x     = (const float*)d_in[0];
  const int*   eidx  = (const int*)d_in[1];
  const float* eattr = (const float*)d_in[2];
  const float* Wn    = (const float*)d_in[3];
  const float* bn    = (const float*)d_in[4];
  const float* We    = (const float*)d_in[5];
  const float* be    = (const float*)d_in[6];
  const float* t     = (const float*)d_in[7];
  const float* W1    = (const float*)d_in[8];
  const float* b1    = (const float*)d_in[9];
  const float* g1    = (const float*)d_in[10];
  const float* c1    = (const float*)d_in[11];
  const float* W2    = (const float*)d_in[12];
  const float* b2    = (const float*)d_in[13];
  const float* gL    = (const float*)d_in[14];
  const float* bL    = (const float*)d_in[15];
  const float* Wo    = (const float*)d_in[16];
  const float* bo    = (const float*)d_in[17];
  float* out = (float*)d_out;

  const int* srcp = eidx;
  const int* dstp = eidx + NE;

  char* p = (char*)d_ws;
  auto alloc = [&](size_t bytes) {
    char* r = p;
    p += (bytes + 255) & ~(size_t)255;
    return r;
  };
  int*  deg     = (int*)alloc((size_t)NN * 4);
  int*  rowptr  = (int*)alloc((size_t)(NN + 1) * 4);
  int*  cursor  = (int*)alloc((size_t)NN * 4);
  int2* csr_se  = (int2*)alloc((size_t)NE * 8);
  float* bufA   = (float*)alloc((size_t)NN * HD * 4);
  float* bufB   = (float*)alloc((size_t)NN * HD * 4);
  float* hbuf   = (float*)alloc((size_t)NN * HD * 4);

  // CSR build (per call — d_ws is re-poisoned before every launch)
  hipLaunchKernelGGL(zero_int_kernel, dim3((NN + 255) / 256), dim3(256), 0, stream, deg, NN);
  hipLaunchKernelGGL(count_kernel, dim3((NE + 255) / 256), dim3(256), 0, stream, dstp, deg);
  hipLaunchKernelGGL(scan_kernel, dim3(1), dim3(1024), 0, stream, deg, rowptr, cursor);
  hipLaunchKernelGGL(scatter_kernel, dim3((NE + 255) / 256), dim3(256), 0, stream, srcp, dstp,
                     cursor, csr_se);

  // encoder
  hipLaunchKernelGGL(encoder_kernel, dim3(NN / 4), dim3(256), 0, stream, x, Wn, bn, bufA);

  // layer 0: x = conv(x)
  hipLaunchKernelGGL(conv_kernel, dim3(NN / 4), dim3(256), 0, stream, bufA, (const float*)nullptr,
                     bufB, rowptr, csr_se, eattr, We, be, t, 0, W1, b1, g1, c1, W2, b2);
  // layer 1: x = x + conv(relu(LN(x)))
  hipLaunchKernelGGL(lnrelu_kernel, dim3(NN / 4), dim3(256), 0, stream, bufB, gL, bL, 1, hbuf);
  hipLaunchKernelGGL(conv_kernel, dim3(NN / 4), dim3(256), 0, stream, hbuf, bufB, bufA, rowptr,
                     csr_se, eattr, We, be, t, 1, W1, b1, g1, c1, W2, b2);
  // layer 2
  hipLaunchKernelGGL(lnrelu_kernel, dim3(NN / 4), dim3(256), 0, stream, bufA, gL, bL, 2, hbuf);
  hipLaunchKernelGGL(conv_kernel, dim3(NN / 4), dim3(256), 0, stream, hbuf, bufA, bufB, rowptr,
                     csr_se, eattr, We, be, t, 2, W1, b1, g1, c1, W2, b2);
  // layer 3
  hipLaunchKernelGGL(lnrelu_kernel, dim3(NN / 4), dim3(256), 0, stream, bufB, gL, bL, 3, hbuf);
  hipLaunchKernelGGL(conv_kernel, dim3(NN / 4), dim3(256), 0, stream, hbuf, bufB, bufA, rowptr,
                     csr_se, eattr, We, be, t, 3, W1, b1, g1, c1, W2, b2);

  // head
  hipLaunchKernelGGL(head_kernel, dim3(NN / 4), dim3(256), 0, stream, bufA, gL, bL, Wo, bo, out);
}

// Round 2
// 919.049 us; speedup vs baseline: 1.3275x; 1.3275x over previous
//
#include <hip/hip_runtime.h>

#define NN 50000
#define NE 800000
#define HD 64

__device__ __forceinline__ float wave_sum(float v) {
#pragma unroll
  for (int off = 32; off > 0; off >>= 1) v += __shfl_xor(v, off, 64);
  return v;
}

// ---------------- CSR build ----------------
__global__ void zero_int_kernel(int* __restrict__ p, int n) {
  int i = blockIdx.x * blockDim.x + threadIdx.x;
  if (i < n) p[i] = 0;
}

__global__ void count_kernel(const int* __restrict__ dst, int* __restrict__ deg) {
  int e = blockIdx.x * blockDim.x + threadIdx.x;
  if (e < NE) atomicAdd(&deg[dst[e]], 1);
}

__global__ __launch_bounds__(1024) void scan_kernel(const int* __restrict__ deg,
                                                    int* __restrict__ rowptr,
                                                    int* __restrict__ cursor) {
  __shared__ int part[1024];
  const int t = threadIdx.x;
  const int chunk = (NN + 1023) / 1024;
  const int lo = min(t * chunk, NN);
  const int hi = min(lo + chunk, NN);
  int sum = 0;
  for (int i = lo; i < hi; ++i) sum += deg[i];
  part[t] = sum;
  __syncthreads();
  for (int off = 1; off < 1024; off <<= 1) {
    int mine = part[t];
    int add = (t >= off) ? part[t - off] : 0;
    __syncthreads();
    part[t] = mine + add;
    __syncthreads();
  }
  int base = (t > 0) ? part[t - 1] : 0;
  for (int i = lo; i < hi; ++i) {
    rowptr[i] = base;
    cursor[i] = base;
    base += deg[i];
  }
  if (t == 0) rowptr[NN] = part[1023];
}

// scatter edges into CSR order AND reorder edge_attr into CSR order (sequential
// read of eattr, one-time random 32B write; amortized over 4 conv layers)
__global__ void scatter_kernel(const int* __restrict__ src, const int* __restrict__ dst,
                               const float4* __restrict__ eattr, int* __restrict__ cursor,
                               int* __restrict__ csr_src, float4* __restrict__ csr_ea) {
  int e = blockIdx.x * blockDim.x + threadIdx.x;
  if (e < NE) {
    int d = dst[e];
    int pos = atomicAdd(&cursor[d], 1);
    csr_src[pos] = src[e];
    float4 a = eattr[2 * e];
    float4 b = eattr[2 * e + 1];
    csr_ea[2 * pos] = a;
    csr_ea[2 * pos + 1] = b;
  }
}

// ---------------- node encoder: x[N,128] @ Wn[128,64] + bn ----------------
__global__ __launch_bounds__(256) void encoder_kernel(const float* __restrict__ x,
                                                      const float* __restrict__ Wn,
                                                      const float* __restrict__ bn,
                                                      float* __restrict__ out) {
  const int w = threadIdx.x >> 6, h = threadIdx.x & 63;
  const int v = blockIdx.x * 4 + w;
  __shared__ float sx[4][128];
  sx[w][h] = x[(size_t)v * 128 + h];
  sx[w][64 + h] = x[(size_t)v * 128 + 64 + h];
  __syncthreads();
  float acc = bn[h];
#pragma unroll 8
  for (int k = 0; k < 128; ++k) acc += sx[w][k] * Wn[k * 64 + h];
  out[(size_t)v * 64 + h] = acc;
}

// ---------------- GENConv: online per-channel segment softmax + fused MLP
//                  + fused epilogue relu(LayerNorm(.)) for the next stage ----------------
__global__ __launch_bounds__(256) void conv_kernel(
    const float* __restrict__ in,      // conv input [N,64] (gather table + root residual)
    const float* __restrict__ resid,   // outer residual x (null for layer 0)
    float* __restrict__ outp,          // [N,64] new x (may be null if not needed)
    float* __restrict__ lnout,         // [N,64] relu(LN(new x)) for next conv / head
    const float* __restrict__ gLl, const float* __restrict__ bLl,  // LN params (offset)
    const int* __restrict__ rowptr, const int* __restrict__ csr_src,
    const float4* __restrict__ csr_ea, // [E,8] CSR-ordered edge attrs
    const float* __restrict__ We,      // [8,64]
    const float* __restrict__ be,      // [64]
    const float* __restrict__ tptr, int layer,
    const float* __restrict__ W1b, const float* __restrict__ b1b,
    const float* __restrict__ g1b, const float* __restrict__ c1b,
    const float* __restrict__ W2b, const float* __restrict__ b2b) {
  const int w = threadIdx.x >> 6, h = threadIdx.x & 63;
  const int v = blockIdx.x * 4 + w;
  const float* W1 = W1b + layer * 64 * 128;
  const float* b1 = b1b + layer * 128;
  const float* g1 = g1b + layer * 128;
  const float* c1 = c1b + layer * 128;
  const float* W2 = W2b + layer * 128 * 64;
  const float* b2 = b2b + layer * 64;
  const float t = tptr[layer];

  float we[8];
#pragma unroll
  for (int k = 0; k < 8; ++k) we[k] = We[k * 64 + h];
  const float beh = be[h];

  // online softmax aggregation over in-edges (per-lane == per-channel),
  // 4x unrolled so the 4 edges' loads are independent (MLP for latency hiding)
  const int i0 = __builtin_amdgcn_readfirstlane(rowptr[v]);
  const int i1 = __builtin_amdgcn_readfirstlane(rowptr[v + 1]);
  float m = -1e30f, s = 0.f, o = 0.f;
  int i = i0;
  for (; i + 4 <= i1; i += 4) {
    const int s0 = csr_src[i + 0], s1 = csr_src[i + 1];
    const int s2 = csr_src[i + 2], s3 = csr_src[i + 3];
    const float4 a0 = csr_ea[2 * i + 0], b0 = csr_ea[2 * i + 1];
    const float4 a1 = csr_ea[2 * i + 2], b1 = csr_ea[2 * i + 3];
    const float4 a2 = csr_ea[2 * i + 4], b2 = csr_ea[2 * i + 5];
    const float4 a3 = csr_ea[2 * i + 6], b3 = csr_ea[2 * i + 7];
    const float x0 = in[(size_t)s0 * 64 + h];
    const float x1 = in[(size_t)s1 * 64 + h];
    const float x2 = in[(size_t)s2 * 64 + h];
    const float x3 = in[(size_t)s3 * 64 + h];
    float e0 = beh + a0.x * we[0] + a0.y * we[1] + a0.z * we[2] + a0.w * we[3]
                   + b0.x * we[4] + b0.y * we[5] + b0.z * we[6] + b0.w * we[7];
    float e1 = beh + a1.x * we[0] + a1.y * we[1] + a1.z * we[2] + a1.w * we[3]
                   + b1.x * we[4] + b1.y * we[5] + b1.z * we[6] + b1.w * we[7];
    float e2 = beh + a2.x * we[0] + a2.y * we[1] + a2.z * we[2] + a2.w * we[3]
                   + b2.x * we[4] + b2.y * we[5] + b2.z * we[6] + b2.w * we[7];
    float e3 = beh + a3.x * we[0] + a3.y * we[1] + a3.z * we[2] + a3.w * we[3]
                   + b3.x * we[4] + b3.y * we[5] + b3.z * we[6] + b3.w * we[7];
    const float g0 = fmaxf(x0 + e0, 0.f) + 1e-7f;
    const float g1v = fmaxf(x1 + e1, 0.f) + 1e-7f;
    const float g2 = fmaxf(x2 + e2, 0.f) + 1e-7f;
    const float g3 = fmaxf(x3 + e3, 0.f) + 1e-7f;
    const float l0 = g0 * t, l1 = g1v * t, l2 = g2 * t, l3 = g3 * t;
    const float mx = fmaxf(fmaxf(l0, l1), fmaxf(l2, l3));
    const float mn = fmaxf(m, mx);
    const float c = __expf(m - mn);
    const float p0 = __expf(l0 - mn), p1 = __expf(l1 - mn);
    const float p2 = __expf(l2 - mn), p3 = __expf(l3 - mn);
    s = s * c + ((p0 + p1) + (p2 + p3));
    o = o * c + ((g0 * p0 + g1v * p1) + (g2 * p2 + g3 * p3));
    m = mn;
  }
  for (; i < i1; ++i) {
    const int sv = csr_src[i];
    const float4 a = csr_ea[2 * i], b = csr_ea[2 * i + 1];
    const float xv = in[(size_t)sv * 64 + h];
    float eh = beh + a.x * we[0] + a.y * we[1] + a.z * we[2] + a.w * we[3]
                   + b.x * we[4] + b.y * we[5] + b.z * we[6] + b.w * we[7];
    const float g = fmaxf(xv + eh, 0.f) + 1e-7f;
    const float l = g * t;
    const float mn = fmaxf(m, l);
    const float c = __expf(m - mn);
    const float p = __expf(l - mn);
    s = s * c + p;
    o = o * c + g * p;
    m = mn;
  }
  float agg = o / (s + 1e-16f) + in[(size_t)v * 64 + h];  // root residual

  // MLP: Linear(64,128) -> LN -> ReLU -> Linear(128,64)
  __shared__ float sh[4][64];
  __shared__ float sh2[4][128];
  sh[w][h] = agg;
  __syncthreads();
  float u0 = b1[h], u1 = b1[64 + h];
#pragma unroll 8
  for (int k = 0; k < 64; ++k) {
    float a = sh[w][k];
    u0 += a * W1[k * 128 + h];
    u1 += a * W1[k * 128 + 64 + h];
  }
  float mu = wave_sum(u0 + u1) * (1.f / 128.f);
  float d0 = u0 - mu, d1 = u1 - mu;
  float var = wave_sum(d0 * d0 + d1 * d1) * (1.f / 128.f);
  float r = rsqrtf(var + 1e-5f);
  float h0 = fmaxf(d0 * r * g1[h] + c1[h], 0.f);
  float h1 = fmaxf(d1 * r * g1[64 + h] + c1[64 + h], 0.f);
  sh2[w][h] = h0;
  sh2[w][64 + h] = h1;
  __syncthreads();
  float acc = b2[h];
#pragma unroll 8
  for (int k = 0; k < 128; ++k) acc += sh2[w][k] * W2[k * 64 + h];
  if (resid) acc += resid[(size_t)v * 64 + h];
  if (outp) outp[(size_t)v * 64 + h] = acc;

  // fused relu(LayerNorm(acc)) for the next stage
  float mu2 = wave_sum(acc) * (1.f / 64.f);
  float dd = acc - mu2;
  float vv = wave_sum(dd * dd) * (1.f / 64.f);
  float rr = rsqrtf(vv + 1e-5f);
  lnout[(size_t)v * 64 + h] = fmaxf(dd * rr * gLl[h] + bLl[h], 0.f);
}

// ---------------- head: (pre-activated input) @ Wo[64,112] + bo ----------------
__global__ __launch_bounds__(256) void head_kernel(const float* __restrict__ x,
                                                   const float* __restrict__ Wo,
                                                   const float* __restrict__ bo,
                                                   float* __restrict__ out) {
  const int w = threadIdx.x >> 6, h = threadIdx.x & 63;
  const int v = blockIdx.x * 4 + w;
  __shared__ float sh[4][64];
  sh[w][h] = x[(size_t)v * 64 + h];
  __syncthreads();
  float o0 = bo[h];
  float o1 = (h < 48) ? bo[64 + h] : 0.f;
  for (int k = 0; k < 64; ++k) {
    float a = sh[w][k];
    o0 += a * Wo[k * 112 + h];
    if (h < 48) o1 += a * Wo[k * 112 + 64 + h];
  }
  out[(size_t)v * 112 + h] = o0;
  if (h < 48) out[(size_t)v * 112 + 64 + h] = o1;
}

extern "C" void kernel_launch(void* const* d_in, const int* in_sizes, int n_in,
                              void* d_out, int out_size, void* d_ws, size_t ws_size,
                              hipStream_t stream) {
  const float* x     = (const float*)d_in[0];
  const int*   eidx  = (const int*)d_in[1];
  const float* eattr = (const float*)d_in[2];
  const float* Wn    = (const float*)d_in[3];
  const float* bn    = (const float*)d_in[4];
  const float* We    = (const float*)d_in[5];
  const float* be    = (const float*)d_in[6];
  const float* t     = (const float*)d_in[7];
  const float* W1    = (const float*)d_in[8];
  const float* b1    = (const float*)d_in[9];
  const float* g1    = (const float*)d_in[10];
  const float* c1    = (const float*)d_in[11];
  const float* W2    = (const float*)d_in[12];
  const float* b2    = (const float*)d_in[13];
  const float* gL    = (const float*)d_in[14];
  const float* bL    = (const float*)d_in[15];
  const float* Wo    = (const float*)d_in[16];
  const float* bo    = (const float*)d_in[17];
  float* out = (float*)d_out;

  const int* srcp = eidx;
  const int* dstp = eidx + NE;

  char* p = (char*)d_ws;
  auto alloc = [&](size_t bytes) {
    char* r = p;
    p += (bytes + 255) & ~(size_t)255;
    return r;
  };
  int*    deg     = (int*)alloc((size_t)NN * 4);
  int*    rowptr  = (int*)alloc((size_t)(NN + 1) * 4);
  int*    cursor  = (int*)alloc((size_t)NN * 4);
  int*    csr_src = (int*)alloc((size_t)NE * 4);
  float4* csr_ea  = (float4*)alloc((size_t)NE * 32);
  float*  bufA    = (float*)alloc((size_t)NN * HD * 4);
  float*  bufB    = (float*)alloc((size_t)NN * HD * 4);
  float*  hbuf    = (float*)alloc((size_t)NN * HD * 4);
  float*  hbuf2   = (float*)alloc((size_t)NN * HD * 4);

  // CSR build (per call — d_ws is re-poisoned before every launch)
  hipLaunchKernelGGL(zero_int_kernel, dim3((NN + 255) / 256), dim3(256), 0, stream, deg, NN);
  hipLaunchKernelGGL(count_kernel, dim3((NE + 255) / 256), dim3(256), 0, stream, dstp, deg);
  hipLaunchKernelGGL(scan_kernel, dim3(1), dim3(1024), 0, stream, deg, rowptr, cursor);
  hipLaunchKernelGGL(scatter_kernel, dim3((NE + 255) / 256), dim3(256), 0, stream, srcp, dstp,
                     (const float4*)eattr, cursor, csr_src, csr_ea);

  // encoder
  hipLaunchKernelGGL(encoder_kernel, dim3(NN / 4), dim3(256), 0, stream, x, Wn, bn, bufA);

  // layer 0: x = conv(x);       lnout = relu(LN(x, gL[1]))
  hipLaunchKernelGGL(conv_kernel, dim3(NN / 4), dim3(256), 0, stream, bufA,
                     (const float*)nullptr, bufB, hbuf, gL + 64, bL + 64, rowptr, csr_src,
                     (const float4*)csr_ea, We, be, t, 0, W1, b1, g1, c1, W2, b2);
  // layer 1: x = x + conv(h);   lnout = relu(LN(x, gL[2]))
  hipLaunchKernelGGL(conv_kernel, dim3(NN / 4), dim3(256), 0, stream, hbuf, bufB, bufA, hbuf2,
                     gL + 128, bL + 128, rowptr, csr_src, (const float4*)csr_ea, We, be, t, 1,
                     W1, b1, g1, c1, W2, b2);
  // layer 2
  hipLaunchKernelGGL(conv_kernel, dim3(NN / 4), dim3(256), 0, stream, hbuf2, bufA, bufB, hbuf,
                     gL + 192, bL + 192, rowptr, csr_src, (const float4*)csr_ea, We, be, t, 2,
                     W1, b1, g1, c1, W2, b2);
  // layer 3: final x not needed; lnout = relu(LN(x, gL[0])) feeds the head
  hipLaunchKernelGGL(conv_kernel, dim3(NN / 4), dim3(256), 0, stream, hbuf, bufB,
                     (float*)nullptr, hbuf2, gL, bL, rowptr, csr_src, (const float4*)csr_ea,
                     We, be, t, 3, W1, b1, g1, c1, W2, b2);

  // head
  hipLaunchKernelGGL(head_kernel, dim3(NN / 4), dim3(256), 0, stream, hbuf2, Wo, bo, out);
}